// Round 7
// baseline (215.326 us; speedup 1.0000x reference)
//
#include <hip/hip_runtime.h>

#define NBATCH 32
#define SEQ    2048
#define NU     512

typedef __attribute__((ext_vector_type(8))) short bf16x8;
typedef __attribute__((ext_vector_type(4))) float f32x4;

__device__ __forceinline__ short bf16_rne(float f) {
  union { float f; unsigned u; } v; v.f = f;
  unsigned r = v.u + 0x7fffu + ((v.u >> 16) & 1u);
  return (short)(r >> 16);
}

// pack bf16(lo), bf16(hi) (truncation) into one u32 via a single v_perm_b32
__device__ __forceinline__ unsigned pk2(float lo, float hi) {
  return __builtin_amdgcn_perm(__float_as_uint(hi), __float_as_uint(lo), 0x07060302u);
}

__device__ __forceinline__ float fast_tanh(float x) {
  float ax = __builtin_fabsf(x);
  float t  = __expf(-2.0f * ax);
  float r  = (1.0f - t) / (1.0f + t);
  return x < 0.0f ? -r : r;
}

// ---------- fused prep ----------
// blocks 0..1023: Wt[col*512 + k] = bf16(W[k*512 + col])  (plain transpose)
// blocks 1024..1087: first[b][u] = s_prev[b]@U + U_bias + W_bias
__global__ __launch_bounds__(256) void prep_all(const float* __restrict__ W,
                                                const float* __restrict__ sp,
                                                const float* __restrict__ U,
                                                const float* __restrict__ Ub,
                                                const float* __restrict__ Wb,
                                                short* __restrict__ Wt,
                                                float* __restrict__ first) {
  __shared__ float srow[NU];
  if (blockIdx.x < 1024) {
    int idx = blockIdx.x * 256 + threadIdx.x;
    int col = idx >> 9, k = idx & 511;
    Wt[idx] = bf16_rne(W[(size_t)k * NU + col]);
  } else {
    int blk = blockIdx.x - 1024;
    int b = blk >> 1, half = blk & 1, t = threadIdx.x;
    srow[t]       = sp[b * NU + t];
    srow[t + 256] = sp[b * NU + t + 256];
    __syncthreads();
    int col = half * 256 + t;
    float acc = Ub[col] + Wb[col];
    #pragma unroll 8
    for (int k = 0; k < NU; ++k) acc += srow[k] * U[(size_t)k * NU + col];
    first[b * NU + col] = acc;
  }
}

// ---------- main: barrier-free all-register GEMM + fused tanh*V ----------
// Wave tile 64 rows x 64 cols via 16x16x32 bf16 MFMA (acc[4][4] f32x4 = 64 regs).
// A (h rows) and B (Wt cols) loaded DIRECTLY from global per k-tile — no LDS,
// no __syncthreads in the loop, waves fully independent.
// Fragment mappings (verified on-device in R1, absmax 1.5e-5):
//   A: lane l holds h[row + (l&15)][kt*32 + (l>>4)*8 .. +8]  (8 floats -> bf16x8)
//   B: lane l holds Wt[col + (l&15)][kt*32 + (l>>4)*8 .. +8] (bf16x8, 16B load)
//   C: row = (l>>4)*4 + r, col = l&15
__global__ __launch_bounds__(256, 3) void attn_main(
    const float* __restrict__ h,      // (65536, 512) fp32
    const short* __restrict__ Wt,     // (512 cols x 512 k) bf16
    const float* __restrict__ first,  // (B, 512) incl. U_bias + W_bias
    const float* __restrict__ V,      // (512)
    float* __restrict__ s0)           // (65536) score accumulator (pre-zeroed)
{
  __shared__ float scores_lds[256];

  const int tid  = threadIdx.x;
  const int lane = tid & 63;
  const int w    = tid >> 6;
  const int lr   = lane & 15, lg = lane >> 4;

  // XCD swizzle: xcd = bid&7 (HW round-robin). Give each XCD 32 contiguous
  // row-blocks; within an XCD the 8 col-groups of one row-block are adjacent
  // in dispatch order -> h panel read 8x but 7 are L2 hits.
  const int bid = blockIdx.x;
  const int xcd = bid & 7, seq = bid >> 3;
  const int rb  = xcd * 32 + (seq >> 3);   // 0..255 row-block (256 rows each)
  const int cg  = seq & 7;                 // 0..7 col-group (64 cols each)
  const int rowbase = rb * 256 + w * 64;   // this wave's 64 rows
  const int b = rb >> 3;                   // batch (2048 rows per batch)

  const float* hbase = h  + (size_t)(rowbase + lr) * NU + lg * 8;
  const short* wbase = Wt + (size_t)(cg * 64 + lr) * NU + lg * 8;

  f32x4 acc[4][4];
  #pragma unroll
  for (int rc = 0; rc < 4; ++rc)
    #pragma unroll
    for (int cc = 0; cc < 4; ++cc)
      acc[rc][cc] = (f32x4){0.f, 0.f, 0.f, 0.f};

  #pragma unroll 2
  for (int kt = 0; kt < 16; ++kt) {
    bf16x8 af[4], bf[4];
    #pragma unroll
    for (int cc = 0; cc < 4; ++cc)
      bf[cc] = *reinterpret_cast<const bf16x8*>(wbase + (size_t)cc * 16 * NU + kt * 32);
    #pragma unroll
    for (int rc = 0; rc < 4; ++rc) {
      const float* p = hbase + (size_t)rc * 16 * NU + kt * 32;
      float4 x0 = *reinterpret_cast<const float4*>(p);
      float4 x1 = *reinterpret_cast<const float4*>(p + 4);
      uint4 u;
      u.x = pk2(x0.x, x0.y); u.y = pk2(x0.z, x0.w);
      u.z = pk2(x1.x, x1.y); u.w = pk2(x1.z, x1.w);
      af[rc] = *reinterpret_cast<bf16x8*>(&u);
    }
    #pragma unroll
    for (int rc = 0; rc < 4; ++rc)
      #pragma unroll
      for (int cc = 0; cc < 4; ++cc)
        acc[rc][cc] = __builtin_amdgcn_mfma_f32_16x16x32_bf16(af[rc], bf[cc], acc[rc][cc], 0, 0, 0);
  }

  // ---- epilogue: tanh + V, reduce over this wave's 64 cols -> per-row partials
  float fv[4], vv[4];
  #pragma unroll
  for (int cc = 0; cc < 4; ++cc) {
    int col = cg * 64 + cc * 16 + lr;
    fv[cc] = first[b * NU + col];
    vv[cc] = V[col];
  }
  #pragma unroll
  for (int rc = 0; rc < 4; ++rc) {
    f32x4 p;
    #pragma unroll
    for (int r = 0; r < 4; ++r) {
      float s = 0.f;
      #pragma unroll
      for (int cc = 0; cc < 4; ++cc)
        s += vv[cc] * fast_tanh(fv[cc] + acc[rc][cc][r]);
      p[r] = s;
    }
    // reduce across the 16 cols held by lanes lr=0..15
    #pragma unroll
    for (int m = 1; m < 16; m <<= 1) {
      #pragma unroll
      for (int r = 0; r < 4; ++r) p[r] += __shfl_xor(p[r], m, 64);
    }
    if (lr == 0)  // rows rc*16 + lg*4 + (0..3)
      *reinterpret_cast<f32x4*>(&scores_lds[w * 64 + rc * 16 + lg * 4]) = p;
  }
  __syncthreads();
  atomicAdd(&s0[rb * 256 + tid], scores_lds[tid]);
}

// ---------- softmax over S per batch (in-place in d_out) + context ----------
__global__ __launch_bounds__(256) void softmax_ctx(const float* __restrict__ sp,
                                                   float* __restrict__ out) {
  const int b = blockIdx.x;
  const int t = threadIdx.x;
  float* wgt = out + NBATCH * NU + (size_t)b * SEQ;
  __shared__ float red[4];

  float v[8];
  float mx = -1e30f;
  #pragma unroll
  for (int i = 0; i < 8; ++i) { v[i] = wgt[t + i * 256]; mx = fmaxf(mx, v[i]); }
  #pragma unroll
  for (int m = 1; m < 64; m <<= 1) mx = fmaxf(mx, __shfl_xor(mx, m, 64));
  if ((t & 63) == 0) red[t >> 6] = mx;
  __syncthreads();
  mx = fmaxf(fmaxf(red[0], red[1]), fmaxf(red[2], red[3]));
  __syncthreads();

  float se = 0.f;
  #pragma unroll
  for (int i = 0; i < 8; ++i) { v[i] = __expf(v[i] - mx); se += v[i]; }
  #pragma unroll
  for (int m = 1; m < 64; m <<= 1) se += __shfl_xor(se, m, 64);
  if ((t & 63) == 0) red[t >> 6] = se;
  __syncthreads();
  se = red[0] + red[1] + red[2] + red[3];
  __syncthreads();

  const float inv = 1.0f / se;
  float sw = 0.f;
  #pragma unroll
  for (int i = 0; i < 8; ++i) { float wi = v[i] * inv; wgt[t + i * 256] = wi; sw += wi; }
  #pragma unroll
  for (int m = 1; m < 64; m <<= 1) sw += __shfl_xor(sw, m, 64);
  if ((t & 63) == 0) red[t >> 6] = sw;
  __syncthreads();
  sw = red[0] + red[1] + red[2] + red[3];

  out[b * NU + t]       = sp[b * NU + t] * sw;
  out[b * NU + t + 256] = sp[b * NU + t + 256] * sw;
}

extern "C" void kernel_launch(void* const* d_in, const int* in_sizes, int n_in,
                              void* d_out, int out_size, void* d_ws, size_t ws_size,
                              hipStream_t stream) {
  (void)in_sizes; (void)n_in; (void)out_size; (void)ws_size;
  const float* s_prev = (const float*)d_in[0];
  const float* h      = (const float*)d_in[1];
  const float* Wk     = (const float*)d_in[2];
  const float* Wb     = (const float*)d_in[3];
  const float* Uk     = (const float*)d_in[4];
  const float* Ub     = (const float*)d_in[5];
  const float* Vk     = (const float*)d_in[6];
  // d_in[7] = V_bias: softmax-shift-invariant, does not affect outputs.

  float* out   = (float*)d_out;
  float* first = (float*)d_ws;                    // 64 KB
  short* Wt    = (short*)((char*)d_ws + 65536);   // 512 KB
  float* s0    = out + NBATCH * NU;               // score accumulator in weights slot

  hipMemsetAsync(s0, 0, (size_t)NBATCH * SEQ * sizeof(float), stream);
  prep_all   <<<1088, 256, 0, stream>>>(Wk, s_prev, Uk, Ub, Wb, Wt, first);
  attn_main  <<<2048, 256, 0, stream>>>(h, Wt, first, Vk, s0);
  softmax_ctx<<<  32, 256, 0, stream>>>(s_prev, out);
}

// Round 8
// 130.748 us; speedup vs baseline: 1.6469x; 1.6469x over previous
//
#include <hip/hip_runtime.h>

#define NBATCH 32
#define SEQ    2048
#define NU     512

typedef __attribute__((ext_vector_type(8))) short bf16x8;
typedef __attribute__((ext_vector_type(4))) float f32x4;

__device__ __forceinline__ short bf16_rne(float f) {
  union { float f; unsigned u; } v; v.f = f;
  unsigned r = v.u + 0x7fffu + ((v.u >> 16) & 1u);
  return (short)(r >> 16);
}

// pack bf16(lo), bf16(hi) (truncation) into one u32 via a single v_perm_b32
__device__ __forceinline__ unsigned pk2(float lo, float hi) {
  return __builtin_amdgcn_perm(__float_as_uint(hi), __float_as_uint(lo), 0x07060302u);
}

__device__ __forceinline__ float fast_tanh(float x) {
  float ax = __builtin_fabsf(x);
  float t  = __expf(-2.0f * ax);
  float r  = (1.0f - t) / (1.0f + t);
  return x < 0.0f ? -r : r;
}

// ---------- fused prep ----------
// blocks 0..1023: WtSw[col*512 + j] = bf16(W[j ^ ((col&7)<<3)][col])
//   (XOR involution baked into global layout; kernel stages linearly into LDS and
//    reads at j ^ ((col&7)<<3) -> original k, conflict-free banks)
// blocks 1024..1087: first[b][u] = s_prev[b]@U + U_bias + W_bias
__global__ __launch_bounds__(256) void prep_all(const float* __restrict__ W,
                                                const float* __restrict__ sp,
                                                const float* __restrict__ U,
                                                const float* __restrict__ Ub,
                                                const float* __restrict__ Wb,
                                                short* __restrict__ WtSw,
                                                float* __restrict__ first) {
  __shared__ float srow[NU];
  if (blockIdx.x < 1024) {
    int idx = blockIdx.x * 256 + threadIdx.x;
    int col = idx >> 9, j = idx & 511;
    int ksrc = j ^ ((col & 7) << 3);
    WtSw[idx] = bf16_rne(W[(size_t)ksrc * NU + col]);
  } else {
    int blk = blockIdx.x - 1024;
    int b = blk >> 1, half = blk & 1, t = threadIdx.x;
    srow[t]       = sp[b * NU + t];
    srow[t + 256] = sp[b * NU + t + 256];
    __syncthreads();
    int col = half * 256 + t;
    float acc = Ub[col] + Wb[col];
    #pragma unroll 8
    for (int k = 0; k < NU; ++k) acc += srow[k] * U[(size_t)k * NU + col];
    first[b * NU + col] = acc;
  }
}

// ---------- main: W-stationary, stage-once, barrier-free ----------
// Grid 256 blocks (1/CU, 128 KB LDS each). Block = 8 waves, col-group of 128 cols.
// Each wave independently processes 2 panels of 64 rows x 128 cols:
//   A-frags straight from global h (16B/lane coalesced-by-row, layout proven R1/R7),
//   B-frags from LDS-resident W slice (XOR-swizzled, 2-way banks = free).
// ONE __syncthreads total (after W staging). acc[4][8] f32x4 = 128 VGPR.
__global__ __launch_bounds__(512, 2) void attn_main(
    const float* __restrict__ h,      // (65536, 512) fp32
    const short* __restrict__ WtSw,   // pre-swizzled (512 cols x 512 k) bf16
    const float* __restrict__ first,  // (B, 512) incl. U_bias + W_bias
    const float* __restrict__ V,      // (512)
    float* __restrict__ s0)           // (65536) score accumulator (pre-zeroed)
{
  __shared__ short Wlds[128 * NU];    // 128 KB

  const int tid  = threadIdx.x;
  const int lane = tid & 63;
  const int w    = tid >> 6;          // 0..7
  const int lr   = lane & 15, lg = lane >> 4;

  const int bid = blockIdx.x;
  const int cg  = bid & 3;            // 128-col group
  const int blk = bid >> 2;           // 0..63 row-super-block (1024 rows)

  // ---- stage the block's W slice once (linear copy, coalesced)
  {
    const short* src = WtSw + (size_t)cg * 128 * NU;
    #pragma unroll
    for (int i = 0; i < 16; ++i) {
      int o = i * 4096 + tid * 8;
      *reinterpret_cast<uint4*>(&Wlds[o]) = *reinterpret_cast<const uint4*>(src + o);
    }
  }
  __syncthreads();

  // ---- per-lane constants
  const int sw = (lr & 7) << 4;                 // byte XOR within W row
  int bbase[8];
  #pragma unroll
  for (int cc = 0; cc < 8; ++cc) bbase[cc] = (cc * 16 + lr) * 1024;  // bytes

  float fv[8], vv[8];
  const int b0 = blk >> 1;                      // batch = row/2048 = blk*1024/2048
  #pragma unroll
  for (int cc = 0; cc < 8; ++cc) {
    int col = cg * 128 + cc * 16 + lr;
    fv[cc] = first[b0 * NU + col];              // blk covers one batch (1024 rows within)
    vv[cc] = V[col];
  }

  const char* wbytes = reinterpret_cast<const char*>(Wlds);

  // ---- 2 independent panels per wave
  for (int pi = 0; pi < 2; ++pi) {
    const int panel = blk * 16 + w * 2 + pi;    // 0..1023
    const int prow  = panel * 64;

    const float* hrow0 = h + (size_t)(prow +  0 + lr) * NU + lg * 8;
    const float* hrow1 = h + (size_t)(prow + 16 + lr) * NU + lg * 8;
    const float* hrow2 = h + (size_t)(prow + 32 + lr) * NU + lg * 8;
    const float* hrow3 = h + (size_t)(prow + 48 + lr) * NU + lg * 8;

    f32x4 acc[4][8];
    #pragma unroll
    for (int rc = 0; rc < 4; ++rc)
      #pragma unroll
      for (int cc = 0; cc < 8; ++cc)
        acc[rc][cc] = (f32x4){0.f, 0.f, 0.f, 0.f};

    #pragma unroll 2
    for (int kt = 0; kt < 16; ++kt) {
      bf16x8 af[4], bf[8];
      {
        const float* p0 = hrow0 + kt * 32;
        const float* p1 = hrow1 + kt * 32;
        const float* p2 = hrow2 + kt * 32;
        const float* p3 = hrow3 + kt * 32;
        float4 a0 = *reinterpret_cast<const float4*>(p0);
        float4 a1 = *reinterpret_cast<const float4*>(p0 + 4);
        float4 b1 = *reinterpret_cast<const float4*>(p1);
        float4 b2 = *reinterpret_cast<const float4*>(p1 + 4);
        float4 c1 = *reinterpret_cast<const float4*>(p2);
        float4 c2 = *reinterpret_cast<const float4*>(p2 + 4);
        float4 d1 = *reinterpret_cast<const float4*>(p3);
        float4 d2 = *reinterpret_cast<const float4*>(p3 + 4);
        uint4 u;
        u.x = pk2(a0.x, a0.y); u.y = pk2(a0.z, a0.w);
        u.z = pk2(a1.x, a1.y); u.w = pk2(a1.z, a1.w);
        af[0] = *reinterpret_cast<bf16x8*>(&u);
        u.x = pk2(b1.x, b1.y); u.y = pk2(b1.z, b1.w);
        u.z = pk2(b2.x, b2.y); u.w = pk2(b2.z, b2.w);
        af[1] = *reinterpret_cast<bf16x8*>(&u);
        u.x = pk2(c1.x, c1.y); u.y = pk2(c1.z, c1.w);
        u.z = pk2(c2.x, c2.y); u.w = pk2(c2.z, c2.w);
        af[2] = *reinterpret_cast<bf16x8*>(&u);
        u.x = pk2(d1.x, d1.y); u.y = pk2(d1.z, d1.w);
        u.z = pk2(d2.x, d2.y); u.w = pk2(d2.z, d2.w);
        af[3] = *reinterpret_cast<bf16x8*>(&u);
      }
      const int kofs = ((kt * 64 + lg * 16) ^ sw);
      #pragma unroll
      for (int cc = 0; cc < 8; ++cc)
        bf[cc] = *reinterpret_cast<const bf16x8*>(wbytes + bbase[cc] + kofs);
      #pragma unroll
      for (int rc = 0; rc < 4; ++rc)
        #pragma unroll
        for (int cc = 0; cc < 8; ++cc)
          acc[rc][cc] = __builtin_amdgcn_mfma_f32_16x16x32_bf16(af[rc], bf[cc], acc[rc][cc], 0, 0, 0);
    }

    // ---- epilogue: tanh + V, reduce over 128 cols -> 64 row partials, atomic add
    #pragma unroll
    for (int rc = 0; rc < 4; ++rc) {
      f32x4 p;
      #pragma unroll
      for (int r = 0; r < 4; ++r) {
        float s = 0.f;
        #pragma unroll
        for (int cc = 0; cc < 8; ++cc)
          s += vv[cc] * fast_tanh(fv[cc] + acc[rc][cc][r]);
        p[r] = s;
      }
      #pragma unroll
      for (int m = 1; m < 16; m <<= 1) {
        #pragma unroll
        for (int r = 0; r < 4; ++r) p[r] += __shfl_xor(p[r], m, 64);
      }
      if (lr == 0) {
        #pragma unroll
        for (int r = 0; r < 4; ++r)
          atomicAdd(&s0[prow + rc * 16 + lg * 4 + r], p[r]);
      }
    }
  }
}

// ---------- softmax over S per batch (in-place in d_out) + context ----------
__global__ __launch_bounds__(256) void softmax_ctx(const float* __restrict__ sp,
                                                   float* __restrict__ out) {
  const int b = blockIdx.x;
  const int t = threadIdx.x;
  float* wgt = out + NBATCH * NU + (size_t)b * SEQ;
  __shared__ float red[4];

  float v[8];
  float mx = -1e30f;
  #pragma unroll
  for (int i = 0; i < 8; ++i) { v[i] = wgt[t + i * 256]; mx = fmaxf(mx, v[i]); }
  #pragma unroll
  for (int m = 1; m < 64; m <<= 1) mx = fmaxf(mx, __shfl_xor(mx, m, 64));
  if ((t & 63) == 0) red[t >> 6] = mx;
  __syncthreads();
  mx = fmaxf(fmaxf(red[0], red[1]), fmaxf(red[2], red[3]));
  __syncthreads();

  float se = 0.f;
  #pragma unroll
  for (int i = 0; i < 8; ++i) { v[i] = __expf(v[i] - mx); se += v[i]; }
  #pragma unroll
  for (int m = 1; m < 64; m <<= 1) se += __shfl_xor(se, m, 64);
  if ((t & 63) == 0) red[t >> 6] = se;
  __syncthreads();
  se = red[0] + red[1] + red[2] + red[3];
  __syncthreads();

  const float inv = 1.0f / se;
  float sw = 0.f;
  #pragma unroll
  for (int i = 0; i < 8; ++i) { float wi = v[i] * inv; wgt[t + i * 256] = wi; sw += wi; }
  #pragma unroll
  for (int m = 1; m < 64; m <<= 1) sw += __shfl_xor(sw, m, 64);
  if ((t & 63) == 0) red[t >> 6] = sw;
  __syncthreads();
  sw = red[0] + red[1] + red[2] + red[3];

  out[b * NU + t]       = sp[b * NU + t] * sw;
  out[b * NU + t + 256] = sp[b * NU + t + 256] * sw;
}

extern "C" void kernel_launch(void* const* d_in, const int* in_sizes, int n_in,
                              void* d_out, int out_size, void* d_ws, size_t ws_size,
                              hipStream_t stream) {
  (void)in_sizes; (void)n_in; (void)out_size; (void)ws_size;
  const float* s_prev = (const float*)d_in[0];
  const float* h      = (const float*)d_in[1];
  const float* Wk     = (const float*)d_in[2];
  const float* Wb     = (const float*)d_in[3];
  const float* Uk     = (const float*)d_in[4];
  const float* Ub     = (const float*)d_in[5];
  const float* Vk     = (const float*)d_in[6];
  // d_in[7] = V_bias: softmax-shift-invariant, does not affect outputs.

  float* out   = (float*)d_out;
  float* first = (float*)d_ws;                    // 64 KB
  short* WtSw  = (short*)((char*)d_ws + 65536);   // 512 KB
  float* s0    = out + NBATCH * NU;               // score accumulator in weights slot

  hipMemsetAsync(s0, 0, (size_t)NBATCH * SEQ * sizeof(float), stream);
  prep_all   <<<1088, 256, 0, stream>>>(Wk, s_prev, Uk, Ub, Wb, WtSw, first);
  attn_main  <<< 256, 512, 0, stream>>>(h, WtSw, first, Vk, s0);
  softmax_ctx<<<  32, 256, 0, stream>>>(s_prev, out);
}

// Round 9
// 114.486 us; speedup vs baseline: 1.8808x; 1.1420x over previous
//
#include <hip/hip_runtime.h>

#define NBATCH 32
#define SEQ    2048
#define NU     512

typedef __attribute__((ext_vector_type(8))) short bf16x8;
typedef __attribute__((ext_vector_type(4))) float f32x4;

__device__ __forceinline__ short bf16_rne(float f) {
  union { float f; unsigned u; } v; v.f = f;
  unsigned r = v.u + 0x7fffu + ((v.u >> 16) & 1u);
  return (short)(r >> 16);
}

// pack bf16(lo), bf16(hi) (truncation) into one u32 via a single v_perm_b32
__device__ __forceinline__ unsigned pk2(float lo, float hi) {
  return __builtin_amdgcn_perm(__float_as_uint(hi), __float_as_uint(lo), 0x07060302u);
}

__device__ __forceinline__ float fast_tanh(float x) {
  float ax = __builtin_fabsf(x);
  float t  = __expf(-2.0f * ax);
  float r  = (1.0f - t) / (1.0f + t);
  return x < 0.0f ? -r : r;
}

// ---------- fused prep ----------
// blocks 0..1023: WtSw[col*512 + j] = bf16(W[j ^ ((col&7)<<3)][col])
// blocks 1024..1087: first[b][u] = s_prev[b]@U + U_bias + W_bias
__global__ __launch_bounds__(256) void prep_all(const float* __restrict__ W,
                                                const float* __restrict__ sp,
                                                const float* __restrict__ U,
                                                const float* __restrict__ Ub,
                                                const float* __restrict__ Wb,
                                                short* __restrict__ WtSw,
                                                float* __restrict__ first) {
  __shared__ float srow[NU];
  if (blockIdx.x < 1024) {
    int idx = blockIdx.x * 256 + threadIdx.x;
    int col = idx >> 9, j = idx & 511;
    int ksrc = j ^ ((col & 7) << 3);
    WtSw[idx] = bf16_rne(W[(size_t)ksrc * NU + col]);
  } else {
    int blk = blockIdx.x - 1024;
    int b = blk >> 1, half = blk & 1, t = threadIdx.x;
    srow[t]       = sp[b * NU + t];
    srow[t + 256] = sp[b * NU + t + 256];
    __syncthreads();
    int col = half * 256 + t;
    float acc = Ub[col] + Wb[col];
    #pragma unroll 8
    for (int k = 0; k < NU; ++k) acc += srow[k] * U[(size_t)k * NU + col];
    first[b * NU + col] = acc;
  }
}

// ---------- main: W-stationary, stage-once, barrier-free, XCD-local rows ----------
// Grid 256 (1 block/CU, all resident). Block = 8 waves, 128-col group.
// KEY (R9): cg = bid>>6, blk = bid&63 -> the 4 col-group blocks sharing a
// row-panel have bid%8 == blk%8 == same XCD; they co-travel, so the h panel
// is fetched from HBM once per XCD and served from L2 for the other 3.
__global__ __launch_bounds__(512, 2) void attn_main(
    const float* __restrict__ h,      // (65536, 512) fp32
    const short* __restrict__ WtSw,   // pre-swizzled (512 cols x 512 k) bf16
    const float* __restrict__ first,  // (B, 512) incl. U_bias + W_bias
    const float* __restrict__ V,      // (512)
    float* __restrict__ s0)           // (65536) score accumulator (pre-zeroed)
{
  __shared__ short Wlds[128 * NU];    // 128 KB

  const int tid  = threadIdx.x;
  const int lane = tid & 63;
  const int w    = tid >> 6;          // 0..7
  const int lr   = lane & 15, lg = lane >> 4;

  const int bid = blockIdx.x;
  const int cg  = bid >> 6;           // 128-col group (0..3)
  const int blk = bid & 63;           // row-super-block (1024 rows); XCD = blk%8

  // ---- stage the block's W slice once (linear copy, coalesced)
  {
    const short* src = WtSw + (size_t)cg * 128 * NU;
    #pragma unroll
    for (int i = 0; i < 16; ++i) {
      int o = i * 4096 + tid * 8;
      *reinterpret_cast<uint4*>(&Wlds[o]) = *reinterpret_cast<const uint4*>(src + o);
    }
  }
  __syncthreads();

  // ---- per-lane constants
  const int sw = (lr & 7) << 4;                 // byte XOR within W row
  int bbase[8];
  #pragma unroll
  for (int cc = 0; cc < 8; ++cc) bbase[cc] = (cc * 16 + lr) * 1024;  // bytes

  float fv[8], vv[8];
  const int b0 = blk >> 1;                      // batch (1024 rows per blk)
  #pragma unroll
  for (int cc = 0; cc < 8; ++cc) {
    int col = cg * 128 + cc * 16 + lr;
    fv[cc] = first[b0 * NU + col];
    vv[cc] = V[col];
  }

  const char* wbytes = reinterpret_cast<const char*>(Wlds);

  // ---- 2 independent panels per wave
  for (int pi = 0; pi < 2; ++pi) {
    const int panel = blk * 16 + w * 2 + pi;    // 0..1023
    const int prow  = panel * 64;

    const float* hrow0 = h + (size_t)(prow +  0 + lr) * NU + lg * 8;
    const float* hrow1 = h + (size_t)(prow + 16 + lr) * NU + lg * 8;
    const float* hrow2 = h + (size_t)(prow + 32 + lr) * NU + lg * 8;
    const float* hrow3 = h + (size_t)(prow + 48 + lr) * NU + lg * 8;

    f32x4 acc[4][8];
    #pragma unroll
    for (int rc = 0; rc < 4; ++rc)
      #pragma unroll
      for (int cc = 0; cc < 8; ++cc)
        acc[rc][cc] = (f32x4){0.f, 0.f, 0.f, 0.f};

    #pragma unroll 2
    for (int kt = 0; kt < 16; ++kt) {
      bf16x8 af[4], bf[8];
      {
        const float* p0 = hrow0 + kt * 32;
        const float* p1 = hrow1 + kt * 32;
        const float* p2 = hrow2 + kt * 32;
        const float* p3 = hrow3 + kt * 32;
        float4 a0 = *reinterpret_cast<const float4*>(p0);
        float4 a1 = *reinterpret_cast<const float4*>(p0 + 4);
        float4 b1 = *reinterpret_cast<const float4*>(p1);
        float4 b2 = *reinterpret_cast<const float4*>(p1 + 4);
        float4 c1 = *reinterpret_cast<const float4*>(p2);
        float4 c2 = *reinterpret_cast<const float4*>(p2 + 4);
        float4 d1 = *reinterpret_cast<const float4*>(p3);
        float4 d2 = *reinterpret_cast<const float4*>(p3 + 4);
        uint4 u;
        u.x = pk2(a0.x, a0.y); u.y = pk2(a0.z, a0.w);
        u.z = pk2(a1.x, a1.y); u.w = pk2(a1.z, a1.w);
        af[0] = *reinterpret_cast<bf16x8*>(&u);
        u.x = pk2(b1.x, b1.y); u.y = pk2(b1.z, b1.w);
        u.z = pk2(b2.x, b2.y); u.w = pk2(b2.z, b2.w);
        af[1] = *reinterpret_cast<bf16x8*>(&u);
        u.x = pk2(c1.x, c1.y); u.y = pk2(c1.z, c1.w);
        u.z = pk2(c2.x, c2.y); u.w = pk2(c2.z, c2.w);
        af[2] = *reinterpret_cast<bf16x8*>(&u);
        u.x = pk2(d1.x, d1.y); u.y = pk2(d1.z, d1.w);
        u.z = pk2(d2.x, d2.y); u.w = pk2(d2.z, d2.w);
        af[3] = *reinterpret_cast<bf16x8*>(&u);
      }
      const int kofs = ((kt * 64 + lg * 16) ^ sw);
      #pragma unroll
      for (int cc = 0; cc < 8; ++cc)
        bf[cc] = *reinterpret_cast<const bf16x8*>(wbytes + bbase[cc] + kofs);
      #pragma unroll
      for (int rc = 0; rc < 4; ++rc)
        #pragma unroll
        for (int cc = 0; cc < 8; ++cc)
          acc[rc][cc] = __builtin_amdgcn_mfma_f32_16x16x32_bf16(af[rc], bf[cc], acc[rc][cc], 0, 0, 0);
    }

    // ---- epilogue: tanh + V, reduce over 128 cols -> 64 row partials, atomic add
    #pragma unroll
    for (int rc = 0; rc < 4; ++rc) {
      f32x4 p;
      #pragma unroll
      for (int r = 0; r < 4; ++r) {
        float s = 0.f;
        #pragma unroll
        for (int cc = 0; cc < 8; ++cc)
          s += vv[cc] * fast_tanh(fv[cc] + acc[rc][cc][r]);
        p[r] = s;
      }
      #pragma unroll
      for (int m = 1; m < 16; m <<= 1) {
        #pragma unroll
        for (int r = 0; r < 4; ++r) p[r] += __shfl_xor(p[r], m, 64);
      }
      if (lr == 0) {
        #pragma unroll
        for (int r = 0; r < 4; ++r)
          atomicAdd(&s0[prow + rc * 16 + lg * 4 + r], p[r]);
      }
    }
  }
}

// ---------- softmax over S per batch (in-place in d_out) + context ----------
__global__ __launch_bounds__(256) void softmax_ctx(const float* __restrict__ sp,
                                                   float* __restrict__ out) {
  const int b = blockIdx.x;
  const int t = threadIdx.x;
  float* wgt = out + NBATCH * NU + (size_t)b * SEQ;
  __shared__ float red[4];

  float v[8];
  float mx = -1e30f;
  #pragma unroll
  for (int i = 0; i < 8; ++i) { v[i] = wgt[t + i * 256]; mx = fmaxf(mx, v[i]); }
  #pragma unroll
  for (int m = 1; m < 64; m <<= 1) mx = fmaxf(mx, __shfl_xor(mx, m, 64));
  if ((t & 63) == 0) red[t >> 6] = mx;
  __syncthreads();
  mx = fmaxf(fmaxf(red[0], red[1]), fmaxf(red[2], red[3]));
  __syncthreads();

  float se = 0.f;
  #pragma unroll
  for (int i = 0; i < 8; ++i) { v[i] = __expf(v[i] - mx); se += v[i]; }
  #pragma unroll
  for (int m = 1; m < 64; m <<= 1) se += __shfl_xor(se, m, 64);
  if ((t & 63) == 0) red[t >> 6] = se;
  __syncthreads();
  se = red[0] + red[1] + red[2] + red[3];
  __syncthreads();

  const float inv = 1.0f / se;
  float sw = 0.f;
  #pragma unroll
  for (int i = 0; i < 8; ++i) { float wi = v[i] * inv; wgt[t + i * 256] = wi; sw += wi; }
  #pragma unroll
  for (int m = 1; m < 64; m <<= 1) sw += __shfl_xor(sw, m, 64);
  if ((t & 63) == 0) red[t >> 6] = sw;
  __syncthreads();
  sw = red[0] + red[1] + red[2] + red[3];

  out[b * NU + t]       = sp[b * NU + t] * sw;
  out[b * NU + t + 256] = sp[b * NU + t + 256] * sw;
}

extern "C" void kernel_launch(void* const* d_in, const int* in_sizes, int n_in,
                              void* d_out, int out_size, void* d_ws, size_t ws_size,
                              hipStream_t stream) {
  (void)in_sizes; (void)n_in; (void)out_size; (void)ws_size;
  const float* s_prev = (const float*)d_in[0];
  const float* h      = (const float*)d_in[1];
  const float* Wk     = (const float*)d_in[2];
  const float* Wb     = (const float*)d_in[3];
  const float* Uk     = (const float*)d_in[4];
  const float* Ub     = (const float*)d_in[5];
  const float* Vk     = (const float*)d_in[6];
  // d_in[7] = V_bias: softmax-shift-invariant, does not affect outputs.

  float* out   = (float*)d_out;
  float* first = (float*)d_ws;                    // 64 KB
  short* WtSw  = (short*)((char*)d_ws + 65536);   // 512 KB
  float* s0    = out + NBATCH * NU;               // score accumulator in weights slot

  hipMemsetAsync(s0, 0, (size_t)NBATCH * SEQ * sizeof(float), stream);
  prep_all   <<<1088, 256, 0, stream>>>(Wk, s_prev, Uk, Ub, Wb, WtSw, first);
  attn_main  <<< 256, 512, 0, stream>>>(h, WtSw, first, Vk, s0);
  softmax_ctx<<<  32, 256, 0, stream>>>(s_prev, out);
}